// Round 20
// baseline (160.220 us; speedup 1.0000x reference)
//
#include <hip/hip_runtime.h>
#include <hip/hip_fp16.h>
#include <stdint.h>

#define IN_F  64
#define MID_F 128
#define OUT_F 32

typedef __bf16 bf16x8 __attribute__((ext_vector_type(8)));
typedef float  f32x4  __attribute__((ext_vector_type(4)));

static __device__ inline unsigned pack2(float a, float b) {
    unsigned short x = __builtin_bit_cast(unsigned short, (__bf16)a);
    unsigned short y = __builtin_bit_cast(unsigned short, (__bf16)b);
    return (unsigned)x | ((unsigned)y << 16);
}

// Native packed-f16 atomic add (no return): one memory-side RMW op for two
// features; r17-measured: NOT write-through (hsum stays cache-resident).
static __device__ inline void atomic_pk_add_h2(__half* addr, float a, float b) {
    const __half2 hv = __floats2half2_rn(a, b);
    const unsigned packed = __builtin_bit_cast(unsigned, hv);
    asm volatile("global_atomic_pk_add_f16 %0, %1, off"
                 :: "v"((void*)addr), "v"(packed)
                 : "memory");
}

// ---------------- combined prep + zero kernel (one dispatch, r19-proven) ----------------
// Block 0: LDS-staged fragment-ordered weight build (coalesced global reads).
// Blocks 1..64: zero counts+hsum with grid-stride uint4 stores.
// Fragment layouts (validated r9/r15/r17):
// w1frag (layer 1, swapped): frag f=t*2+q, lane l: elem j = W1[q*32+lg*8+j][t*16+lr]
// w2frag (layer 2, standard + pi k-map): frag f2=u*4+q, lane l:
//   elem j = W2[((j>>2)*4+q)*16+lg*4+(j&3)][2*lr+u]   (packed-pair column map)
__global__ void prep_zero_kernel(const float* __restrict__ W1,
                                 const float* __restrict__ W2,
                                 unsigned* __restrict__ wbuf,
                                 uint4* __restrict__ zbase, int zlen16) {
    const int t = threadIdx.x;   // 1024 threads

    if (blockIdx.x != 0) {
        const uint4 zero = make_uint4(0u, 0u, 0u, 0u);
        for (int i = (blockIdx.x - 1) * 1024 + t; i < zlen16; i += 64 * 1024)
            zbase[i] = zero;
        return;
    }

    __shared__ float sW1raw[IN_F * MID_F];   // 32 KB
    __shared__ float sW2raw[MID_F * OUT_F];  // 16 KB

    for (int i = t; i < IN_F * MID_F; i += 1024) sW1raw[i] = W1[i];
    for (int i = t; i < MID_F * OUT_F; i += 1024) sW2raw[i] = W2[i];
    __syncthreads();

    {
        const int i = t;
        const int f = i >> 6, l = i & 63;
        const int t1 = f >> 1, q = f & 1, lg = l >> 4, lr = l & 15;
        unsigned r[4];
        #pragma unroll
        for (int jj = 0; jj < 4; ++jj) {
            const int k0 = q * 32 + lg * 8 + 2 * jj;
            const float v0 = sW1raw[k0 * MID_F + t1 * 16 + lr];
            const float v1 = sW1raw[(k0 + 1) * MID_F + t1 * 16 + lr];
            r[jj] = pack2(v0, v1);
        }
        ((uint4*)wbuf)[i] = make_uint4(r[0], r[1], r[2], r[3]);
    }
    if (t < 512) {
        const int i = t;
        const int f = i >> 6, l = i & 63;
        const int u = f >> 2, q = f & 3, lg = l >> 4, lr = l & 15;
        const int pn = 2 * lr + u;              // packed-pair column map
        unsigned r[4];
        #pragma unroll
        for (int jj = 0; jj < 4; ++jj) {
            const int j0 = 2 * jj, j1 = 2 * jj + 1;
            const int ka = ((j0 >> 2) * 4 + q) * 16 + lg * 4 + (j0 & 3);
            const int kb = ((j1 >> 2) * 4 + q) * 16 + lg * 4 + (j1 & 3);
            r[jj] = pack2(sW2raw[ka * OUT_F + pn], sW2raw[kb * OUT_F + pn]);
        }
        ((uint4*)wbuf)[1024 + i] = make_uint4(r[0], r[1], r[2], r[3]);
    }
}

// ---------------- fused streaming MLP, TWO CHUNKS PER WAVE (no loop) ----------------
// r18 lesson: in-order vmcnt retirement means any load issued after an atomic
// waits for the atomic's ack; so all loads first, all atomics last, s_endpgm.
// r20: two chunks (32 rows) per wave halves block count / LDS staging / launch
// overhead while preserving the no-load-after-atomic ordering. Volatile weight
// views stop the 24 fragments from being hoisted across both computes.
__global__ __launch_bounds__(512) void fused_mlp_scatter(
    const float* __restrict__ vecs,
    const int*   __restrict__ sidx,
    const unsigned* __restrict__ wbuf,
    const float* __restrict__ b1, const float* __restrict__ b2,
    __half* __restrict__ hsum, float* __restrict__ counts, int nrows)
{
    __shared__ __align__(16) __bf16 sW1F[16 * 64 * 8];   // 16 KB frag-ordered
    __shared__ __align__(16) __bf16 sW2F[8 * 64 * 8];    //  8 KB frag-ordered
    __shared__ __align__(16) float sB1[MID_F];
    __shared__ __align__(16) float sB2[OUT_F];

    const int tid = threadIdx.x;
    {   // linear 24 KB copy, coalesced, conflict-free (wbuf is L2/L3-resident)
        const uint4* src = (const uint4*)wbuf;
        uint4* w1 = (uint4*)sW1F;
        uint4* w2 = (uint4*)sW2F;
        #pragma unroll
        for (int i = tid; i < 1024; i += 512) w1[i] = src[i];
        if (tid < 512) w2[tid] = src[1024 + tid];
        if (tid < MID_F) sB1[tid] = b1[tid];
        if (tid < OUT_F) sB2[tid] = b2[tid];
    }
    __syncthreads();

    const int lane = tid & 63, wid = tid >> 6;   // wid 0..7
    const int lg = lane >> 4, lr = lane & 15;

    // volatile views: forbid hoisting weight/bias fragments across computes
    const volatile bf16x8* vW1 = (const volatile bf16x8*)sW1F;
    const volatile bf16x8* vW2 = (const volatile bf16x8*)sW2F;
    const volatile f32x4*  vB1 = (const volatile f32x4*)sB1;

    const int nchunk = nrows >> 4;
    const int cA = (blockIdx.x * 8 + wid) * 2;
    if (cA >= nchunk) return;
    const bool hB = (cA + 1) < nchunk;
    const int baseA = cA << 4;
    const int baseB = baseA + 16;

    // ---- ALL loads first (x for both chunks + both seg vectors) ----
    bf16x8 a0A, a1A, a0B, a1B;
    int4 segsA, segsB;
    {
        const float* xrA = vecs + (size_t)(baseA + lr) * IN_F + lg * 8;
        const float* xrB = vecs + (size_t)(baseB + lr) * IN_F + lg * 8;
        f32x4 pa = *(const f32x4*)(xrA);
        f32x4 pb = *(const f32x4*)(xrA + 4);
        f32x4 pc = *(const f32x4*)(xrA + 32);
        f32x4 pd = *(const f32x4*)(xrA + 36);
        f32x4 qa = {0,0,0,0}, qb = {0,0,0,0}, qc = {0,0,0,0}, qd = {0,0,0,0};
        if (hB) {
            qa = *(const f32x4*)(xrB);
            qb = *(const f32x4*)(xrB + 4);
            qc = *(const f32x4*)(xrB + 32);
            qd = *(const f32x4*)(xrB + 36);
        }
        segsA = *(const int4*)(sidx + baseA + lg * 4);
        segsB = hB ? *(const int4*)(sidx + baseB + lg * 4) : make_int4(0, 0, 0, 0);
        #pragma unroll
        for (int j = 0; j < 4; ++j) {
            a0A[j] = (__bf16)pa[j]; a0A[j + 4] = (__bf16)pb[j];
            a1A[j] = (__bf16)pc[j]; a1A[j + 4] = (__bf16)pd[j];
            a0B[j] = (__bf16)qa[j]; a0B[j + 4] = (__bf16)qb[j];
            a1B[j] = (__bf16)qc[j]; a1B[j + 4] = (__bf16)qd[j];
        }
    }

    const float bz0 = sB2[2 * lr], bz1 = sB2[2 * lr + 1];

    // ---- per-chunk compute (interleaved layer1/layer2, r13-validated) ----
    auto compute = [&](bf16x8 a0, bf16x8 a1, f32x4& o0, f32x4& o1) {
        o0 = f32x4{ bz0, bz0, bz0, bz0 };
        o1 = f32x4{ bz1, bz1, bz1, bz1 };
        #pragma unroll
        for (int q = 0; q < 4; ++q) {
            bf16x8 w1a = vW1[(q * 2 + 0) * 64 + lane];
            bf16x8 w1b = vW1[(q * 2 + 1) * 64 + lane];
            f32x4 acc = vB1[(q * 16 + lg * 4) >> 2];
            acc = __builtin_amdgcn_mfma_f32_16x16x32_bf16(w1a, a0, acc, 0, 0, 0);
            acc = __builtin_amdgcn_mfma_f32_16x16x32_bf16(w1b, a1, acc, 0, 0, 0);
            const unsigned p0 = pack2(fmaxf(acc[0], 0.f), fmaxf(acc[1], 0.f));
            const unsigned p1 = pack2(fmaxf(acc[2], 0.f), fmaxf(acc[3], 0.f));
            w1a = vW1[((q + 4) * 2 + 0) * 64 + lane];
            w1b = vW1[((q + 4) * 2 + 1) * 64 + lane];
            acc = vB1[((q + 4) * 16 + lg * 4) >> 2];
            acc = __builtin_amdgcn_mfma_f32_16x16x32_bf16(w1a, a0, acc, 0, 0, 0);
            acc = __builtin_amdgcn_mfma_f32_16x16x32_bf16(w1b, a1, acc, 0, 0, 0);
            const unsigned p2 = pack2(fmaxf(acc[0], 0.f), fmaxf(acc[1], 0.f));
            const unsigned p3 = pack2(fmaxf(acc[2], 0.f), fmaxf(acc[3], 0.f));
            uint4 bi = make_uint4(p0, p1, p2, p3);
            bf16x8 A2 = __builtin_bit_cast(bf16x8, bi);
            bf16x8 w2a = vW2[(0 * 4 + q) * 64 + lane];
            bf16x8 w2b = vW2[(1 * 4 + q) * 64 + lane];
            o0 = __builtin_amdgcn_mfma_f32_16x16x32_bf16(A2, w2a, o0, 0, 0, 0);
            o1 = __builtin_amdgcn_mfma_f32_16x16x32_bf16(A2, w2b, o1, 0, 0, 0);
        }
    };

    f32x4 accA0, accA1, accB0, accB1;
    compute(a0A, a1A, accA0, accA1);
    if (hB) compute(a0B, a1B, accB0, accB1);

    // ---- ALL atomics last (no VMEM load follows; wave exits) ----
    {
        const int sa[4] = { segsA.x, segsA.y, segsA.z, segsA.w };
        #pragma unroll
        for (int r = 0; r < 4; ++r) {
            atomic_pk_add_h2(hsum + (size_t)sa[r] * OUT_F + 2 * lr,
                             accA0[r], accA1[r]);
        }
        const int cs = (lr == 0) ? segsA.x : (lr == 1) ? segsA.y
                     : (lr == 2) ? segsA.z : segsA.w;
        if (lr < 4) atomicAdd(counts + cs, 1.0f);
    }
    if (hB) {
        const int sb[4] = { segsB.x, segsB.y, segsB.z, segsB.w };
        #pragma unroll
        for (int r = 0; r < 4; ++r) {
            atomic_pk_add_h2(hsum + (size_t)sb[r] * OUT_F + 2 * lr,
                             accB0[r], accB1[r]);
        }
        const int cs = (lr == 0) ? segsB.x : (lr == 1) ? segsB.y
                     : (lr == 2) ? segsB.z : segsB.w;
        if (lr < 4) atomicAdd(counts + cs, 1.0f);
    }
}

__global__ __launch_bounds__(256) void finalize_kernel(
    const __half* __restrict__ hsum, const float* __restrict__ counts,
    float* __restrict__ out, int total)
{
    int i = blockIdx.x * 256 + threadIdx.x;
    if (i < total) {
        const float s = __half2float(hsum[i]);
        out[i] = s / fmaxf(counts[i >> 5], 1.0f);
    }
}

extern "C" void kernel_launch(void* const* d_in, const int* in_sizes, int n_in,
                              void* d_out, int out_size, void* d_ws, size_t ws_size,
                              hipStream_t stream)
{
    const float* vecs = (const float*)d_in[0];
    const int*   sidx = (const int*)d_in[1];
    const float* W1 = (const float*)d_in[3];
    const float* b1 = (const float*)d_in[4];
    const float* W2 = (const float*)d_in[5];
    const float* b2 = (const float*)d_in[6];
    float* out = (float*)d_out;

    const int nrows = in_sizes[0] / IN_F;
    const int nseg  = out_size / OUT_F;
    const int nchunk = nrows >> 4;
    const int nblk   = (nchunk + 15) / 16;   // 8 waves/block, 2 chunks/wave

    // workspace layout: [counts nseg*f32][hsum out_size*f16][wbuf 24KB]
    auto algn = [](size_t x) { return (x + 255) & ~(size_t)255; };
    char* w = (char*)d_ws;
    const size_t counts_b = algn((size_t)nseg * 4);
    const size_t hsum_b   = algn((size_t)out_size * sizeof(__half));
    float*    counts = (float*)w;
    __half*   hsum   = (__half*)(w + counts_b);
    unsigned* wbuf   = (unsigned*)(w + counts_b + hsum_b);

    const int zlen16 = (int)((counts_b + hsum_b) / 16);   // uint4 count (256-aligned)

    prep_zero_kernel<<<65, 1024, 0, stream>>>(W1, W2, wbuf, (uint4*)w, zlen16);
    fused_mlp_scatter<<<nblk, 512, 0, stream>>>(vecs, sidx, wbuf, b1, b2,
                                                hsum, counts, nrows);
    finalize_kernel<<<(out_size + 255) / 256, 256, 0, stream>>>(hsum, counts, out, out_size);
}

// Round 21
// 133.950 us; speedup vs baseline: 1.1961x; 1.1961x over previous
//
#include <hip/hip_runtime.h>
#include <hip/hip_fp16.h>
#include <stdint.h>

#define IN_F  64
#define MID_F 128
#define OUT_F 32

typedef __bf16 bf16x8 __attribute__((ext_vector_type(8)));
typedef float  f32x4  __attribute__((ext_vector_type(4)));

static __device__ inline unsigned pack2(float a, float b) {
    unsigned short x = __builtin_bit_cast(unsigned short, (__bf16)a);
    unsigned short y = __builtin_bit_cast(unsigned short, (__bf16)b);
    return (unsigned)x | ((unsigned)y << 16);
}

// Native packed-f16 atomic add (no return): one memory-side RMW op for two
// features; r17-measured: NOT write-through (hsum stays cache-resident).
static __device__ inline void atomic_pk_add_h2(__half* addr, float a, float b) {
    const __half2 hv = __floats2half2_rn(a, b);
    const unsigned packed = __builtin_bit_cast(unsigned, hv);
    asm volatile("global_atomic_pk_add_f16 %0, %1, off"
                 :: "v"((void*)addr), "v"(packed)
                 : "memory");
}

// ---------------- combined prep + zero kernel (one dispatch) ----------------
// Block 0: build fragment-ordered bf16 weights, LDS-staged (coalesced global
// reads; the scattered fragment gather happens in LDS where it's free).
// Blocks 1..64: zero counts+hsum (replaces two hipMemsetAsync dispatches).
//
// Fragment layouts (validated r9/r15/r17):
// w1frag (layer 1, swapped): frag f=t*2+q, lane l: elem j = W1[q*32+lg*8+j][t*16+lr]
// w2frag (layer 2, standard + pi k-map): frag f2=u*4+q, lane l:
//   elem j = W2[((j>>2)*4+q)*16+lg*4+(j&3)][2*lr+u]   (packed-pair column map)
__global__ void prep_zero_kernel(const float* __restrict__ W1,
                                 const float* __restrict__ W2,
                                 unsigned* __restrict__ wbuf,
                                 uint4* __restrict__ zbase, int zlen16) {
    const int t = threadIdx.x;   // 1024 threads

    if (blockIdx.x != 0) {
        // ---- zero counts + hsum, grid-stride uint4 stores ----
        const uint4 zero = make_uint4(0u, 0u, 0u, 0u);
        for (int i = (blockIdx.x - 1) * 1024 + t; i < zlen16; i += 64 * 1024)
            zbase[i] = zero;
        return;
    }

    // ---- block 0: weight prep, LDS-staged ----
    __shared__ float sW1raw[IN_F * MID_F];   // 32 KB
    __shared__ float sW2raw[MID_F * OUT_F];  // 16 KB

    for (int i = t; i < IN_F * MID_F; i += 1024) sW1raw[i] = W1[i];
    for (int i = t; i < MID_F * OUT_F; i += 1024) sW2raw[i] = W2[i];
    __syncthreads();

    {
        const int i = t;
        const int f = i >> 6, l = i & 63;
        const int t1 = f >> 1, q = f & 1, lg = l >> 4, lr = l & 15;
        unsigned r[4];
        #pragma unroll
        for (int jj = 0; jj < 4; ++jj) {
            const int k0 = q * 32 + lg * 8 + 2 * jj;
            const float v0 = sW1raw[k0 * MID_F + t1 * 16 + lr];
            const float v1 = sW1raw[(k0 + 1) * MID_F + t1 * 16 + lr];
            r[jj] = pack2(v0, v1);
        }
        ((uint4*)wbuf)[i] = make_uint4(r[0], r[1], r[2], r[3]);
    }
    if (t < 512) {
        const int i = t;
        const int f = i >> 6, l = i & 63;
        const int u = f >> 2, q = f & 3, lg = l >> 4, lr = l & 15;
        const int pn = 2 * lr + u;              // packed-pair column map
        unsigned r[4];
        #pragma unroll
        for (int jj = 0; jj < 4; ++jj) {
            const int j0 = 2 * jj, j1 = 2 * jj + 1;
            const int ka = ((j0 >> 2) * 4 + q) * 16 + lg * 4 + (j0 & 3);
            const int kb = ((j1 >> 2) * 4 + q) * 16 + lg * 4 + (j1 & 3);
            r[jj] = pack2(sW2raw[ka * OUT_F + pn], sW2raw[kb * OUT_F + pn]);
        }
        ((uint4*)wbuf)[1024 + i] = make_uint4(r[0], r[1], r[2], r[3]);
    }
}

// ---------------- fused streaming MLP, ONE CHUNK PER WAVE (r19, best) ----------------
// In-order vmcnt retirement puts atomic-ack latency on any loop's critical
// path; with no loop, atomics are the last VMEM ops before s_endpgm and the
// coherent-point latency overlaps the next blocks' waves via slot refill
// (wave churn). r20 falsified amortizing 2 chunks/wave: halving churn cost
// more than the staging it saved (134.6 -> 160.2 us).
__global__ __launch_bounds__(512) void fused_mlp_scatter(
    const float* __restrict__ vecs,
    const int*   __restrict__ sidx,
    const unsigned* __restrict__ wbuf,
    const float* __restrict__ b1, const float* __restrict__ b2,
    __half* __restrict__ hsum, float* __restrict__ counts, int nrows)
{
    __shared__ __align__(16) __bf16 sW1F[16 * 64 * 8];   // 16 KB frag-ordered
    __shared__ __align__(16) __bf16 sW2F[8 * 64 * 8];    //  8 KB frag-ordered
    __shared__ __align__(16) float sB1[MID_F];
    __shared__ __align__(16) float sB2[OUT_F];

    const int tid = threadIdx.x;
    {   // linear 24 KB copy, coalesced, conflict-free (wbuf is L2/L3-resident)
        const uint4* src = (const uint4*)wbuf;
        uint4* w1 = (uint4*)sW1F;
        uint4* w2 = (uint4*)sW2F;
        #pragma unroll
        for (int i = tid; i < 1024; i += 512) w1[i] = src[i];
        if (tid < 512) w2[tid] = src[1024 + tid];
        if (tid < MID_F) sB1[tid] = b1[tid];
        if (tid < OUT_F) sB2[tid] = b2[tid];
    }
    __syncthreads();

    const int lane = tid & 63, wid = tid >> 6;   // wid 0..7
    const int lg = lane >> 4, lr = lane & 15;

    // one chunk per wave
    const int c = blockIdx.x * 8 + wid;
    if (c >= (nrows >> 4)) return;
    const int base = c << 4;

    // ---- coalesced x loads; f32 dies immediately into bf16 A-frags ----
    const float* xr = vecs + (size_t)(base + lr) * IN_F + lg * 8;
    bf16x8 a0, a1;
    {
        f32x4 x0a = *(const f32x4*)(xr);
        f32x4 x0b = *(const f32x4*)(xr + 4);
        f32x4 x1a = *(const f32x4*)(xr + 32);
        f32x4 x1b = *(const f32x4*)(xr + 36);
        #pragma unroll
        for (int j = 0; j < 4; ++j) {
            a0[j] = (__bf16)x0a[j]; a0[j + 4] = (__bf16)x0b[j];
            a1[j] = (__bf16)x1a[j]; a1[j + 4] = (__bf16)x1b[j];
        }
    }

    const bf16x8* W1F = (const bf16x8*)sW1F;
    const bf16x8* W2F = (const bf16x8*)sW2F;

    // ---- interleaved layers: per q, produce h-tiles q and q+4, consume
    //      them immediately in the layer-2 MFMA pair ----
    const float bz0 = sB2[2 * lr], bz1 = sB2[2 * lr + 1];
    f32x4 acc2_0 = { bz0, bz0, bz0, bz0 };
    f32x4 acc2_1 = { bz1, bz1, bz1, bz1 };
    #pragma unroll
    for (int q = 0; q < 4; ++q) {
        // layer-1 tile t=q: lane owns h[row lr][feat q*16+lg*4+reg]
        bf16x8 w1a = W1F[(q * 2 + 0) * 64 + lane];
        bf16x8 w1b = W1F[(q * 2 + 1) * 64 + lane];
        f32x4 acc = *(const f32x4*)&sB1[q * 16 + lg * 4];
        acc = __builtin_amdgcn_mfma_f32_16x16x32_bf16(w1a, a0, acc, 0, 0, 0);
        acc = __builtin_amdgcn_mfma_f32_16x16x32_bf16(w1b, a1, acc, 0, 0, 0);
        const unsigned p0 = pack2(fmaxf(acc[0], 0.f), fmaxf(acc[1], 0.f));
        const unsigned p1 = pack2(fmaxf(acc[2], 0.f), fmaxf(acc[3], 0.f));
        // layer-1 tile t=q+4
        w1a = W1F[((q + 4) * 2 + 0) * 64 + lane];
        w1b = W1F[((q + 4) * 2 + 1) * 64 + lane];
        acc = *(const f32x4*)&sB1[(q + 4) * 16 + lg * 4];
        acc = __builtin_amdgcn_mfma_f32_16x16x32_bf16(w1a, a0, acc, 0, 0, 0);
        acc = __builtin_amdgcn_mfma_f32_16x16x32_bf16(w1b, a1, acc, 0, 0, 0);
        const unsigned p2 = pack2(fmaxf(acc[0], 0.f), fmaxf(acc[1], 0.f));
        const unsigned p3 = pack2(fmaxf(acc[2], 0.f), fmaxf(acc[3], 0.f));
        // layer-2 q-slice (standard orientation, zero-shuffle via pi)
        uint4 bi = make_uint4(p0, p1, p2, p3);
        bf16x8 A2 = __builtin_bit_cast(bf16x8, bi);
        bf16x8 w2a = W2F[(0 * 4 + q) * 64 + lane];
        bf16x8 w2b = W2F[(1 * 4 + q) * 64 + lane];
        acc2_0 = __builtin_amdgcn_mfma_f32_16x16x32_bf16(A2, w2a, acc2_0, 0, 0, 0);
        acc2_1 = __builtin_amdgcn_mfma_f32_16x16x32_bf16(A2, w2b, acc2_1, 0, 0, 0);
    }

    // ---- segs loaded late; atomics are the LAST VMEM ops before wave exit ----
    int4 segs = *(const int4*)(sidx + base + lg * 4);   // rows lg*4+0..3
    {
        const int sa[4] = { segs.x, segs.y, segs.z, segs.w };
        #pragma unroll
        for (int r = 0; r < 4; ++r) {
            atomic_pk_add_h2(hsum + (size_t)sa[r] * OUT_F + 2 * lr,
                             acc2_0[r], acc2_1[r]);
        }
        const int cs = (lr == 0) ? segs.x : (lr == 1) ? segs.y
                     : (lr == 2) ? segs.z : segs.w;
        if (lr < 4) atomicAdd(counts + cs, 1.0f);
    }
}

__global__ __launch_bounds__(256) void finalize_kernel(
    const __half* __restrict__ hsum, const float* __restrict__ counts,
    float* __restrict__ out, int total)
{
    int i = blockIdx.x * 256 + threadIdx.x;
    if (i < total) {
        const float s = __half2float(hsum[i]);
        out[i] = s / fmaxf(counts[i >> 5], 1.0f);
    }
}

extern "C" void kernel_launch(void* const* d_in, const int* in_sizes, int n_in,
                              void* d_out, int out_size, void* d_ws, size_t ws_size,
                              hipStream_t stream)
{
    const float* vecs = (const float*)d_in[0];
    const int*   sidx = (const int*)d_in[1];
    const float* W1 = (const float*)d_in[3];
    const float* b1 = (const float*)d_in[4];
    const float* W2 = (const float*)d_in[5];
    const float* b2 = (const float*)d_in[6];
    float* out = (float*)d_out;

    const int nrows = in_sizes[0] / IN_F;
    const int nseg  = out_size / OUT_F;
    const int nchunk = nrows >> 4;
    const int nblk   = (nchunk + 7) / 8;   // 8 waves/block, 1 chunk/wave

    // workspace layout: [counts nseg*f32][hsum out_size*f16][wbuf 24KB]
    auto algn = [](size_t x) { return (x + 255) & ~(size_t)255; };
    char* w = (char*)d_ws;
    const size_t counts_b = algn((size_t)nseg * 4);
    const size_t hsum_b   = algn((size_t)out_size * sizeof(__half));
    float*    counts = (float*)w;
    __half*   hsum   = (__half*)(w + counts_b);
    unsigned* wbuf   = (unsigned*)(w + counts_b + hsum_b);

    const int zlen16 = (int)((counts_b + hsum_b) / 16);   // uint4 count (256-aligned)

    prep_zero_kernel<<<65, 1024, 0, stream>>>(W1, W2, wbuf, (uint4*)w, zlen16);
    fused_mlp_scatter<<<nblk, 512, 0, stream>>>(vecs, sidx, wbuf, b1, b2,
                                                hsum, counts, nrows);
    finalize_kernel<<<(out_size + 255) / 256, 256, 0, stream>>>(hsum, counts, out, out_size);
}